// Round 10
// baseline (829.715 us; speedup 1.0000x reference)
//
#include <hip/hip_runtime.h>

// GCN 3-layer + mean pool, MI355X.
// R1: pool atomics -> segmented reduction (1106 -> 764us).
// R2: k_gemm rewrite 128x64 tile (confirmed R5: gemm left top-5).
// R5: k_agg2 latency-bound, VGPR=12, compiler serialized chains.
// R6: k_agg3 float2: 71 -> 65.5us, VGPR=20, FETCH 188MB (L2 hit ~16%:
//     H=25.6MB vs 4MB per-XCD L2).
// R8 post-mortem: k_agg4 masked 8-batch REGRESSED 65.5 -> 85.7us (VGPR=32,
//     wasted masked gathers, throughput down). Lesson: ILP via unroll loses
//     to the register allocator; L2 misses are structural.
// R9: k_agg5 — (a) MLP from lanes: wave = 4 edge-slots x 16 dims, 4
//     independent gathers per instruction + x2 unroll, shfl_xor reduce,
//     no LDS/barrier; (b) XCD feature-slicing: slice = blockIdx%8 -> each
//     XCD's H footprint = 3.2MB, fits 4MB private L2 (round-robin
//     dispatch heuristic; correctness mapping-independent). colA loads
//     nontemporal to keep L2 for H.
//     (R9 bench: container failed twice = infra; source re-audited for
//      memory safety, resubmitted unchanged.)

constexpr int KDIM = 128;   // inner dim of all three GEMMs
constexpr int NGRAPH = 64;

__global__ void k_init(int* __restrict__ counts, int n) {
  int i = blockIdx.x * blockDim.x + threadIdx.x;
  int stride = gridDim.x * blockDim.x;
  for (int j = i; j < n; j += stride) counts[j] = 0;
}

__global__ void k_hist(const int* __restrict__ src, const int* __restrict__ dst,
                       int* __restrict__ counts, int e, int n) {
  int i = blockIdx.x * blockDim.x + threadIdx.x;
  int stride = gridDim.x * blockDim.x;
  for (int j = i; j < e; j += stride) {
    int s = src[j], d = dst[j];
    if ((unsigned)s < (unsigned)n && (unsigned)d < (unsigned)n)
      atomicAdd(&counts[d], 1);
  }
}

__global__ void k_dis(const int* __restrict__ counts, float* __restrict__ dis, int n) {
  int i = blockIdx.x * blockDim.x + threadIdx.x;
  int stride = gridDim.x * blockDim.x;
  for (int j = i; j < n; j += stride)
    dis[j] = rsqrtf((float)counts[j] + 1.0f);
}

// per-block exclusive scan; blockSums[b] = block total
__global__ void k_scan_block(const int* __restrict__ in, int* __restrict__ outExcl,
                             int* __restrict__ blockSums, int n) {
  __shared__ int s[256];
  int tid = threadIdx.x;
  int i = blockIdx.x * 256 + tid;
  int v = (i < n) ? in[i] : 0;
  int x = v;
  s[tid] = x;
  __syncthreads();
  for (int off = 1; off < 256; off <<= 1) {
    int t = (tid >= off) ? s[tid - off] : 0;
    __syncthreads();
    x += t;
    s[tid] = x;
    __syncthreads();
  }
  if (i < n) outExcl[i] = x - v;
  if (tid == 255) blockSums[blockIdx.x] = x;
}

__global__ void k_scan_offsets(int* __restrict__ bs, int nb) {
  __shared__ int s[256];
  int tid = threadIdx.x;
  int v = (tid < nb) ? bs[tid] : 0;
  int x = v;
  s[tid] = x;
  __syncthreads();
  for (int off = 1; off < 256; off <<= 1) {
    int t = (tid >= off) ? s[tid - off] : 0;
    __syncthreads();
    x += t;
    s[tid] = x;
    __syncthreads();
  }
  if (tid < nb) bs[tid] = x - v;
  if (tid == nb - 1) bs[256] = x;  // total valid edges
}

__global__ void k_scan_add(int* __restrict__ row_start, const int* __restrict__ bs,
                           int* __restrict__ cursor, int n) {
  int i = blockIdx.x * blockDim.x + threadIdx.x;
  int stride = gridDim.x * blockDim.x;
  for (int j = i; j < n; j += stride) {
    int r = row_start[j] + bs[j >> 8];
    row_start[j] = r;
    cursor[j] = r;
  }
  if (i == 0) row_start[n] = bs[256];
}

__global__ void k_scatter(const int* __restrict__ src, const int* __restrict__ dst,
                          int* __restrict__ cursor, int* __restrict__ colA,
                          int e, int n) {
  int i = blockIdx.x * blockDim.x + threadIdx.x;
  int stride = gridDim.x * blockDim.x;
  for (int j = i; j < e; j += stride) {
    int s = src[j], d = dst[j];
    if ((unsigned)s < (unsigned)n && (unsigned)d < (unsigned)n) {
      int pos = atomicAdd(&cursor[d], 1);
      colA[pos] = s;
    }
  }
}

// H = X @ W.  Block tile 128 rows x 64 cols, BK=32. (unchanged from R2)
template <int DOUT>
__global__ __launch_bounds__(256) void k_gemm2(const float* __restrict__ X,
                                               const float* __restrict__ W,
                                               float* __restrict__ H, int n) {
  __shared__ float xT[32][128];  // 16 KB
  __shared__ float Wl[32][64];   // 8 KB
  const int tid = threadIdx.x;
  const int tr = tid & 15;
  const int tc = tid >> 4;
  const int rowBase = blockIdx.x * 128;
  const int colBase = blockIdx.y * 64;

  float acc[8][4];
#pragma unroll
  for (int i = 0; i < 8; ++i)
#pragma unroll
    for (int j = 0; j < 4; ++j) acc[i][j] = 0.f;

  const int sr = tid >> 1;
  const int kh = (tid & 1) * 16;
  const int srow = min(rowBase + sr, n - 1);
  const float* xsrc = X + (size_t)srow * KDIM + kh;

  for (int k0 = 0; k0 < KDIM / 32; ++k0) {
    {
      const float4* s4 = reinterpret_cast<const float4*>(xsrc + k0 * 32);
      float4 v0 = s4[0], v1 = s4[1], v2 = s4[2], v3 = s4[3];
      xT[kh + 0][sr] = v0.x;  xT[kh + 1][sr] = v0.y;
      xT[kh + 2][sr] = v0.z;  xT[kh + 3][sr] = v0.w;
      xT[kh + 4][sr] = v1.x;  xT[kh + 5][sr] = v1.y;
      xT[kh + 6][sr] = v1.z;  xT[kh + 7][sr] = v1.w;
      xT[kh + 8][sr] = v2.x;  xT[kh + 9][sr] = v2.y;
      xT[kh + 10][sr] = v2.z; xT[kh + 11][sr] = v2.w;
      xT[kh + 12][sr] = v3.x; xT[kh + 13][sr] = v3.y;
      xT[kh + 14][sr] = v3.z; xT[kh + 15][sr] = v3.w;
    }
#pragma unroll
    for (int q = 0; q < 2; ++q) {
      int f4 = tid + q * 256;
      int k = f4 >> 4;
      int c4 = f4 & 15;
      *reinterpret_cast<float4*>(&Wl[k][c4 * 4]) = *reinterpret_cast<const float4*>(
          W + (size_t)(k0 * 32 + k) * DOUT + colBase + c4 * 4);
    }
    __syncthreads();
#pragma unroll 8
    for (int k = 0; k < 32; ++k) {
      float4 xa = *reinterpret_cast<const float4*>(&xT[k][tr * 4]);
      float4 xb = *reinterpret_cast<const float4*>(&xT[k][64 + tr * 4]);
      float4 wv = *reinterpret_cast<const float4*>(&Wl[k][tc * 4]);
      const float xs[8] = {xa.x, xa.y, xa.z, xa.w, xb.x, xb.y, xb.z, xb.w};
      const float ws[4] = {wv.x, wv.y, wv.z, wv.w};
#pragma unroll
      for (int i = 0; i < 8; ++i)
#pragma unroll
        for (int j = 0; j < 4; ++j) acc[i][j] = fmaf(xs[i], ws[j], acc[i][j]);
    }
    __syncthreads();
  }

#pragma unroll
  for (int i = 0; i < 8; ++i) {
    int row = rowBase + ((i < 4) ? (tr * 4 + i) : (64 + tr * 4 + i - 4));
    if (row < n) {
      float4 o = {acc[i][0], acc[i][1], acc[i][2], acc[i][3]};
      *reinterpret_cast<float4*>(H + (size_t)row * DOUT + colBase + tc * 4) = o;
    }
  }
}

// R9 aggregation: one wave per (node, 16-dim slice).
// lane = esub(0..3) x dim(0..15): 4 independent edge gathers per
// instruction (+x2 unroll = 8 in flight), no register-pressure fight.
// slice = blockIdx%8-derived -> per-XCD H footprint 3.2MB (fits 4MB L2)
// under round-robin dispatch. shfl_xor reduce; no LDS, no barrier.
template <int D, bool RELU>
__global__ __launch_bounds__(256) void k_agg5(const float* __restrict__ H,
                                              const int* __restrict__ row_start,
                                              const int* __restrict__ colA,
                                              const float* __restrict__ dis,
                                              const float* __restrict__ bias,
                                              float* __restrict__ OUT, int n) {
  constexpr int NS = D / 16;         // 8 (D=128) or 4 (D=64) slices
  constexpr int NPG = 4 * (8 / NS);  // nodes covered per 8-block group
  const int r = blockIdx.x & 7;
  const int nb = blockIdx.x >> 3;
  const int slice = r % NS;
  const int nodeSub = r / NS;
  const int wave = threadIdx.x >> 6;
  const int lane = threadIdx.x & 63;
  const int esub = lane >> 4;
  const int d = lane & 15;
  const int node = nb * NPG + nodeSub * 4 + wave;
  if (node >= n) return;

  const int d0 = slice * 16;
  const int beg = row_start[node];
  const int end = row_start[node + 1];
  const float di = dis[node];
  float acc = 0.f;

  int e = beg + esub;
  for (; e + 4 < end; e += 8) {   // x2 unroll: 8 gathers in flight per wave
    const int s0 = __builtin_nontemporal_load(&colA[e]);
    const int s1 = __builtin_nontemporal_load(&colA[e + 4]);
    const float w0 = dis[s0] * di;
    const float w1 = dis[s1] * di;
    const float h0 = H[(size_t)s0 * D + d0 + d];
    const float h1 = H[(size_t)s1 * D + d0 + d];
    acc = fmaf(h0, w0, acc);
    acc = fmaf(h1, w1, acc);
  }
  for (; e < end; e += 4) {
    const int s0 = __builtin_nontemporal_load(&colA[e]);
    const float w0 = dis[s0] * di;
    acc = fmaf(H[(size_t)s0 * D + d0 + d], w0, acc);
  }

  acc += __shfl_xor(acc, 16);
  acc += __shfl_xor(acc, 32);

  if (esub == 0) {
    const float di2 = di * di;
    float v = acc + H[(size_t)node * D + d0 + d] * di2 + bias[d0 + d];
    if (RELU) v = fmaxf(v, 0.f);
    OUT[(size_t)node * D + d0 + d] = v;
  }
}

// batch sorted -> one block per graph, binary-search range, no atomics.
__global__ __launch_bounds__(256) void k_pool2(const float* __restrict__ F,
                                               const int* __restrict__ batch,
                                               float* __restrict__ out, int n) {
  const int g = blockIdx.x;
  __shared__ int sb[2];
  if (threadIdx.x < 2) {
    int target = g + threadIdx.x;
    int lo = 0, hi = n;
    while (lo < hi) {
      int mid = (lo + hi) >> 1;
      if (batch[mid] < target) lo = mid + 1; else hi = mid;
    }
    sb[threadIdx.x] = lo;
  }
  __syncthreads();
  const int beg = sb[0], end = sb[1];
  const int wave = threadIdx.x >> 6;
  const int lane = threadIdx.x & 63;
  float acc = 0.f;
  for (int node = beg + wave; node < end; node += 4)
    acc += F[(size_t)node * 64 + lane];
  __shared__ float red[4][64];
  red[wave][lane] = acc;
  __syncthreads();
  if (wave == 0) {
    float v = (red[0][lane] + red[1][lane]) + (red[2][lane] + red[3][lane]);
    out[g * 64 + lane] = v / fmaxf((float)(end - beg), 1.f);
  }
}

extern "C" void kernel_launch(void* const* d_in, const int* in_sizes, int n_in,
                              void* d_out, int out_size, void* d_ws, size_t ws_size,
                              hipStream_t stream) {
  const float* x     = (const float*)d_in[0];
  const int*   ei    = (const int*)d_in[1];
  const int*   batch = (const int*)d_in[2];
  const float* W1 = (const float*)d_in[3];
  const float* b1 = (const float*)d_in[4];
  const float* W2 = (const float*)d_in[5];
  const float* b2 = (const float*)d_in[6];
  const float* W3 = (const float*)d_in[7];
  const float* b3 = (const float*)d_in[8];

  const int n = in_sizes[0] / KDIM;   // 50000
  const int e = in_sizes[1] / 2;      // 800000
  const int* src = ei;
  const int* dst = ei + e;

  char* p = (char*)d_ws;
  size_t off = 0;
  auto carve = [&](size_t bytes) {
    char* r = p + off;
    off = (off + bytes + 255) & ~(size_t)255;
    return r;
  };
  float* bufA      = (float*)carve((size_t)n * KDIM * 4);
  float* bufB      = (float*)carve((size_t)n * KDIM * 4);
  float* dis       = (float*)carve((size_t)n * 4);
  int*   counts    = (int*)carve((size_t)n * 4);
  int*   row_start = (int*)carve((size_t)(n + 1) * 4);
  int*   cursor    = (int*)carve((size_t)n * 4);
  int*   colA      = (int*)carve((size_t)e * 4);
  int*   blockSums = (int*)carve(512 * 4);
  (void)ws_size;

  const int nb1 = (n + 255) / 256;
  const int GS = 1024;

  k_init<<<GS, 256, 0, stream>>>(counts, n);
  k_hist<<<GS, 256, 0, stream>>>(src, dst, counts, e, n);
  k_dis<<<nb1, 256, 0, stream>>>(counts, dis, n);
  k_scan_block<<<nb1, 256, 0, stream>>>(counts, row_start, blockSums, n);
  k_scan_offsets<<<1, 256, 0, stream>>>(blockSums, nb1);
  k_scan_add<<<nb1, 256, 0, stream>>>(row_start, blockSums, cursor, n);
  k_scatter<<<GS, 256, 0, stream>>>(src, dst, cursor, colA, e, n);

  const int rowBlocks = (n + 127) / 128;       // 391
  const int aggGrid128 = 8 * ((n + 3) / 4);    // 100000 blocks
  const int aggGrid64  = 8 * ((n + 7) / 8);    // 50000 blocks

  // layer 1
  k_gemm2<128><<<dim3(rowBlocks, 2), 256, 0, stream>>>(x, W1, bufA, n);
  k_agg5<128, true><<<aggGrid128, 256, 0, stream>>>(bufA, row_start, colA, dis, b1, bufB, n);
  // layer 2
  k_gemm2<128><<<dim3(rowBlocks, 2), 256, 0, stream>>>(bufB, W2, bufA, n);
  k_agg5<128, true><<<aggGrid128, 256, 0, stream>>>(bufA, row_start, colA, dis, b2, bufB, n);
  // layer 3
  k_gemm2<64><<<dim3(rowBlocks, 1), 256, 0, stream>>>(bufB, W3, bufA, n);
  k_agg5<64, false><<<aggGrid64, 256, 0, stream>>>(bufA, row_start, colA, dis, b3,
                                                   (float*)d_out, n);
  // pooling
  k_pool2<<<NGRAPH, 256, 0, stream>>>((const float*)d_out, batch,
                                      (float*)d_out + (size_t)n * 64, n);
}

// Round 11
// 514.852 us; speedup vs baseline: 1.6116x; 1.6116x over previous
//
#include <hip/hip_runtime.h>

// GCN 3-layer + mean pool, MI355X.
// R1: pool atomics -> segmented reduction (1106 -> 764us).
// R2: k_gemm rewrite 128x64 tile (confirmed R5: gemm left top-5).
// R5-R10 agg ladder: agg2 71us (VGPR=12, serialized) -> agg3 65.5us
//   (float2, 188MB FETCH @ 2.9 TB/s) -> agg4 85.7us (masked batch, REGRESS)
//   -> agg5 220us (lane-slots+XCD slicing, REGRESS, FETCH UP).
// Conclusion: random-512B L2-miss path saturates ~2.9 TB/s; parallelism
//   beyond agg3's is useless; ONLY bytes matter.
// R11: agg3 structure EXACTLY, but H stored bf16 (RNE) by the GEMMs ->
//   gather bytes halve (256B/row). f32 accum/dis/bias/outputs. Predict
//   agg 65.5 -> ~35-45us, FETCH ~100MB; absmax ~1-3e-3 (tolerance bet).

constexpr int KDIM = 128;   // inner dim of all three GEMMs
constexpr int NGRAPH = 64;

__device__ __forceinline__ unsigned bf16rne(float f) {
  unsigned u = __float_as_uint(f);
  return (u + 0x7fffu + ((u >> 16) & 1u)) >> 16;  // finite values only
}
__device__ __forceinline__ unsigned packbf2(float a, float b) {
  return bf16rne(a) | (bf16rne(b) << 16);
}

__global__ void k_init(int* __restrict__ counts, int n) {
  int i = blockIdx.x * blockDim.x + threadIdx.x;
  int stride = gridDim.x * blockDim.x;
  for (int j = i; j < n; j += stride) counts[j] = 0;
}

__global__ void k_hist(const int* __restrict__ src, const int* __restrict__ dst,
                       int* __restrict__ counts, int e, int n) {
  int i = blockIdx.x * blockDim.x + threadIdx.x;
  int stride = gridDim.x * blockDim.x;
  for (int j = i; j < e; j += stride) {
    int s = src[j], d = dst[j];
    if ((unsigned)s < (unsigned)n && (unsigned)d < (unsigned)n)
      atomicAdd(&counts[d], 1);
  }
}

__global__ void k_dis(const int* __restrict__ counts, float* __restrict__ dis, int n) {
  int i = blockIdx.x * blockDim.x + threadIdx.x;
  int stride = gridDim.x * blockDim.x;
  for (int j = i; j < n; j += stride)
    dis[j] = rsqrtf((float)counts[j] + 1.0f);
}

// per-block exclusive scan; blockSums[b] = block total
__global__ void k_scan_block(const int* __restrict__ in, int* __restrict__ outExcl,
                             int* __restrict__ blockSums, int n) {
  __shared__ int s[256];
  int tid = threadIdx.x;
  int i = blockIdx.x * 256 + tid;
  int v = (i < n) ? in[i] : 0;
  int x = v;
  s[tid] = x;
  __syncthreads();
  for (int off = 1; off < 256; off <<= 1) {
    int t = (tid >= off) ? s[tid - off] : 0;
    __syncthreads();
    x += t;
    s[tid] = x;
    __syncthreads();
  }
  if (i < n) outExcl[i] = x - v;
  if (tid == 255) blockSums[blockIdx.x] = x;
}

__global__ void k_scan_offsets(int* __restrict__ bs, int nb) {
  __shared__ int s[256];
  int tid = threadIdx.x;
  int v = (tid < nb) ? bs[tid] : 0;
  int x = v;
  s[tid] = x;
  __syncthreads();
  for (int off = 1; off < 256; off <<= 1) {
    int t = (tid >= off) ? s[tid - off] : 0;
    __syncthreads();
    x += t;
    s[tid] = x;
    __syncthreads();
  }
  if (tid < nb) bs[tid] = x - v;
  if (tid == nb - 1) bs[256] = x;  // total valid edges
}

__global__ void k_scan_add(int* __restrict__ row_start, const int* __restrict__ bs,
                           int* __restrict__ cursor, int n) {
  int i = blockIdx.x * blockDim.x + threadIdx.x;
  int stride = gridDim.x * blockDim.x;
  for (int j = i; j < n; j += stride) {
    int r = row_start[j] + bs[j >> 8];
    row_start[j] = r;
    cursor[j] = r;
  }
  if (i == 0) row_start[n] = bs[256];
}

__global__ void k_scatter(const int* __restrict__ src, const int* __restrict__ dst,
                          int* __restrict__ cursor, int* __restrict__ colA,
                          int e, int n) {
  int i = blockIdx.x * blockDim.x + threadIdx.x;
  int stride = gridDim.x * blockDim.x;
  for (int j = i; j < e; j += stride) {
    int s = src[j], d = dst[j];
    if ((unsigned)s < (unsigned)n && (unsigned)d < (unsigned)n) {
      int pos = atomicAdd(&cursor[d], 1);
      colA[pos] = s;
    }
  }
}

// H = X @ W.  Block tile 128 rows x 64 cols, BK=32. (R2 structure)
// R11: stores H as bf16 (RNE), packed 4 per uint2 -> halves write traffic
// and halves the downstream gather bytes.
template <int DOUT>
__global__ __launch_bounds__(256) void k_gemm2b(const float* __restrict__ X,
                                                const float* __restrict__ W,
                                                unsigned short* __restrict__ Hb,
                                                int n) {
  __shared__ float xT[32][128];  // 16 KB
  __shared__ float Wl[32][64];   // 8 KB
  const int tid = threadIdx.x;
  const int tr = tid & 15;
  const int tc = tid >> 4;
  const int rowBase = blockIdx.x * 128;
  const int colBase = blockIdx.y * 64;

  float acc[8][4];
#pragma unroll
  for (int i = 0; i < 8; ++i)
#pragma unroll
    for (int j = 0; j < 4; ++j) acc[i][j] = 0.f;

  const int sr = tid >> 1;
  const int kh = (tid & 1) * 16;
  const int srow = min(rowBase + sr, n - 1);
  const float* xsrc = X + (size_t)srow * KDIM + kh;

  for (int k0 = 0; k0 < KDIM / 32; ++k0) {
    {
      const float4* s4 = reinterpret_cast<const float4*>(xsrc + k0 * 32);
      float4 v0 = s4[0], v1 = s4[1], v2 = s4[2], v3 = s4[3];
      xT[kh + 0][sr] = v0.x;  xT[kh + 1][sr] = v0.y;
      xT[kh + 2][sr] = v0.z;  xT[kh + 3][sr] = v0.w;
      xT[kh + 4][sr] = v1.x;  xT[kh + 5][sr] = v1.y;
      xT[kh + 6][sr] = v1.z;  xT[kh + 7][sr] = v1.w;
      xT[kh + 8][sr] = v2.x;  xT[kh + 9][sr] = v2.y;
      xT[kh + 10][sr] = v2.z; xT[kh + 11][sr] = v2.w;
      xT[kh + 12][sr] = v3.x; xT[kh + 13][sr] = v3.y;
      xT[kh + 14][sr] = v3.z; xT[kh + 15][sr] = v3.w;
    }
#pragma unroll
    for (int q = 0; q < 2; ++q) {
      int f4 = tid + q * 256;
      int k = f4 >> 4;
      int c4 = f4 & 15;
      *reinterpret_cast<float4*>(&Wl[k][c4 * 4]) = *reinterpret_cast<const float4*>(
          W + (size_t)(k0 * 32 + k) * DOUT + colBase + c4 * 4);
    }
    __syncthreads();
#pragma unroll 8
    for (int k = 0; k < 32; ++k) {
      float4 xa = *reinterpret_cast<const float4*>(&xT[k][tr * 4]);
      float4 xb = *reinterpret_cast<const float4*>(&xT[k][64 + tr * 4]);
      float4 wv = *reinterpret_cast<const float4*>(&Wl[k][tc * 4]);
      const float xs[8] = {xa.x, xa.y, xa.z, xa.w, xb.x, xb.y, xb.z, xb.w};
      const float ws[4] = {wv.x, wv.y, wv.z, wv.w};
#pragma unroll
      for (int i = 0; i < 8; ++i)
#pragma unroll
        for (int j = 0; j < 4; ++j) acc[i][j] = fmaf(xs[i], ws[j], acc[i][j]);
    }
    __syncthreads();
  }

#pragma unroll
  for (int i = 0; i < 8; ++i) {
    int row = rowBase + ((i < 4) ? (tr * 4 + i) : (64 + tr * 4 + i - 4));
    if (row < n) {
      uint2 o;
      o.x = packbf2(acc[i][0], acc[i][1]);
      o.y = packbf2(acc[i][2], acc[i][3]);
      *reinterpret_cast<uint2*>(Hb + (size_t)row * DOUT + colBase + tc * 4) = o;
    }
  }
}

// R11 aggregation: EXACT agg3 structure (2 waves/node even/odd, x2 unroll,
// LDS combine) with bf16 gather loads. Lane covers 2 consecutive dims
// (D=128: one dword = 2 bf16) or 1 dim (D=64: ushort). f32 accumulate.
template <int D, bool RELU>
__global__ __launch_bounds__(256) void k_agg6(const unsigned short* __restrict__ Hb,
                                              const int* __restrict__ row_start,
                                              const int* __restrict__ colA,
                                              const float* __restrict__ dis,
                                              const float* __restrict__ bias,
                                              float* __restrict__ OUT, int n) {
  const int wave = threadIdx.x >> 6;
  const int lane = threadIdx.x & 63;
  const int slot = wave >> 1;
  const int half = wave & 1;
  const int node = blockIdx.x * 2 + slot;
  constexpr int C = D / 64;  // 2 (D=128) or 1 (D=64)
  __shared__ float red[4][D];

  if (node < n) {
    const int beg = row_start[node];
    const int end = row_start[node + 1];
    const float di = dis[node];
    float acc[C];
#pragma unroll
    for (int c = 0; c < C; ++c) acc[c] = 0.f;

    int e = beg + half;
    for (; e + 2 < end; e += 4) {
      const int s0 = colA[e], s1 = colA[e + 2];
      const float n0 = dis[s0] * di, n1 = dis[s1] * di;
      if constexpr (C == 2) {
        const unsigned u0 =
            reinterpret_cast<const unsigned*>(Hb + (size_t)s0 * D)[lane];
        const unsigned u1 =
            reinterpret_cast<const unsigned*>(Hb + (size_t)s1 * D)[lane];
        acc[0] = fmaf(__uint_as_float(u0 << 16), n0, acc[0]);
        acc[1] = fmaf(__uint_as_float(u0 & 0xffff0000u), n0, acc[1]);
        acc[0] = fmaf(__uint_as_float(u1 << 16), n1, acc[0]);
        acc[1] = fmaf(__uint_as_float(u1 & 0xffff0000u), n1, acc[1]);
      } else {
        const unsigned v0 = Hb[(size_t)s0 * D + lane];
        const unsigned v1 = Hb[(size_t)s1 * D + lane];
        acc[0] = fmaf(__uint_as_float(v0 << 16), n0, acc[0]);
        acc[0] = fmaf(__uint_as_float(v1 << 16), n1, acc[0]);
      }
    }
    for (; e < end; e += 2) {
      const int s0 = colA[e];
      const float n0 = dis[s0] * di;
      if constexpr (C == 2) {
        const unsigned u0 =
            reinterpret_cast<const unsigned*>(Hb + (size_t)s0 * D)[lane];
        acc[0] = fmaf(__uint_as_float(u0 << 16), n0, acc[0]);
        acc[1] = fmaf(__uint_as_float(u0 & 0xffff0000u), n0, acc[1]);
      } else {
        const unsigned v0 = Hb[(size_t)s0 * D + lane];
        acc[0] = fmaf(__uint_as_float(v0 << 16), n0, acc[0]);
      }
    }
#pragma unroll
    for (int c = 0; c < C; ++c) red[wave][C * lane + c] = acc[c];
  } else {
#pragma unroll
    for (int c = 0; c < C; ++c) red[wave][C * lane + c] = 0.f;
  }
  __syncthreads();
  if (half == 0 && node < n) {
    const float di = dis[node];
    const float di2 = di * di;
    float hs[C];
    if constexpr (C == 2) {
      const unsigned u =
          reinterpret_cast<const unsigned*>(Hb + (size_t)node * D)[lane];
      hs[0] = __uint_as_float(u << 16);
      hs[1] = __uint_as_float(u & 0xffff0000u);
    } else {
      hs[0] = __uint_as_float((unsigned)Hb[(size_t)node * D + lane] << 16);
    }
    float* o = OUT + (size_t)node * D + C * lane;
    const float* bi = bias + C * lane;
#pragma unroll
    for (int c = 0; c < C; ++c) {
      float v = red[wave][C * lane + c] + red[wave + 1][C * lane + c] +
                hs[c] * di2 + bi[c];
      if (RELU) v = fmaxf(v, 0.f);
      o[c] = v;
    }
  }
}

// batch sorted -> one block per graph, binary-search range, no atomics.
__global__ __launch_bounds__(256) void k_pool2(const float* __restrict__ F,
                                               const int* __restrict__ batch,
                                               float* __restrict__ out, int n) {
  const int g = blockIdx.x;
  __shared__ int sb[2];
  if (threadIdx.x < 2) {
    int target = g + threadIdx.x;
    int lo = 0, hi = n;
    while (lo < hi) {
      int mid = (lo + hi) >> 1;
      if (batch[mid] < target) lo = mid + 1; else hi = mid;
    }
    sb[threadIdx.x] = lo;
  }
  __syncthreads();
  const int beg = sb[0], end = sb[1];
  const int wave = threadIdx.x >> 6;
  const int lane = threadIdx.x & 63;
  float acc = 0.f;
  for (int node = beg + wave; node < end; node += 4)
    acc += F[(size_t)node * 64 + lane];
  __shared__ float red[4][64];
  red[wave][lane] = acc;
  __syncthreads();
  if (wave == 0) {
    float v = (red[0][lane] + red[1][lane]) + (red[2][lane] + red[3][lane]);
    out[g * 64 + lane] = v / fmaxf((float)(end - beg), 1.f);
  }
}

extern "C" void kernel_launch(void* const* d_in, const int* in_sizes, int n_in,
                              void* d_out, int out_size, void* d_ws, size_t ws_size,
                              hipStream_t stream) {
  const float* x     = (const float*)d_in[0];
  const int*   ei    = (const int*)d_in[1];
  const int*   batch = (const int*)d_in[2];
  const float* W1 = (const float*)d_in[3];
  const float* b1 = (const float*)d_in[4];
  const float* W2 = (const float*)d_in[5];
  const float* b2 = (const float*)d_in[6];
  const float* W3 = (const float*)d_in[7];
  const float* b3 = (const float*)d_in[8];

  const int n = in_sizes[0] / KDIM;   // 50000
  const int e = in_sizes[1] / 2;      // 800000
  const int* src = ei;
  const int* dst = ei + e;

  char* p = (char*)d_ws;
  size_t off = 0;
  auto carve = [&](size_t bytes) {
    char* r = p + off;
    off = (off + bytes + 255) & ~(size_t)255;
    return r;
  };
  unsigned short* Hb = (unsigned short*)carve((size_t)n * KDIM * 2);  // bf16 H
  float* F           = (float*)carve((size_t)n * KDIM * 4);           // f32 relu out
  float* dis         = (float*)carve((size_t)n * 4);
  int*   counts      = (int*)carve((size_t)n * 4);
  int*   row_start   = (int*)carve((size_t)(n + 1) * 4);
  int*   cursor      = (int*)carve((size_t)n * 4);
  int*   colA        = (int*)carve((size_t)e * 4);
  int*   blockSums   = (int*)carve(512 * 4);
  (void)ws_size;

  const int nb1 = (n + 255) / 256;
  const int GS = 1024;

  k_init<<<GS, 256, 0, stream>>>(counts, n);
  k_hist<<<GS, 256, 0, stream>>>(src, dst, counts, e, n);
  k_dis<<<nb1, 256, 0, stream>>>(counts, dis, n);
  k_scan_block<<<nb1, 256, 0, stream>>>(counts, row_start, blockSums, n);
  k_scan_offsets<<<1, 256, 0, stream>>>(blockSums, nb1);
  k_scan_add<<<nb1, 256, 0, stream>>>(row_start, blockSums, cursor, n);
  k_scatter<<<GS, 256, 0, stream>>>(src, dst, cursor, colA, e, n);

  const int rowBlocks = (n + 127) / 128;  // 391
  const int aggGrid = (n + 1) / 2;        // 2 nodes per block

  // layer 1
  k_gemm2b<128><<<dim3(rowBlocks, 2), 256, 0, stream>>>(x, W1, Hb, n);
  k_agg6<128, true><<<aggGrid, 256, 0, stream>>>(Hb, row_start, colA, dis, b1, F, n);
  // layer 2
  k_gemm2b<128><<<dim3(rowBlocks, 2), 256, 0, stream>>>(F, W2, Hb, n);
  k_agg6<128, true><<<aggGrid, 256, 0, stream>>>(Hb, row_start, colA, dis, b2, F, n);
  // layer 3
  k_gemm2b<64><<<dim3(rowBlocks, 1), 256, 0, stream>>>(F, W3, Hb, n);
  k_agg6<64, false><<<aggGrid, 256, 0, stream>>>(Hb, row_start, colA, dis, b3,
                                                 (float*)d_out, n);
  // pooling
  k_pool2<<<NGRAPH, 256, 0, stream>>>((const float*)d_out, batch,
                                      (float*)d_out + (size_t)n * 64, n);
}

// Round 12
// 446.296 us; speedup vs baseline: 1.8591x; 1.1536x over previous
//
#include <hip/hip_runtime.h>

// GCN 3-layer + mean pool, MI355X.
// R1: pool atomics -> segmented reduction (1106 -> 764us).
// R2: k_gemm rewrite 128x64 tile (confirmed R5: gemm left top-5).
// R5-R11 agg ladder: agg2 71 (VGPR12) -> agg3 65.5 (VGPR20, 2 indep accs,
//   2.9TB/s) -> agg4 85.7 (masked, REGRESS) -> agg5 220 (REGRESS) ->
//   agg6 bf16 72.9us: FETCH halved 188->85MB but time UP => NOT byte-bound.
//   Model: latency-bound; throughput = waves x chains / latency; compiler
//   collapses chains sharing an accumulator (VGPR 12) — only agg3's two
//   INDEPENDENT accumulators ever sustained >2 chains.
// R12: k_agg7 — each wave owns TWO nodes (A,B), interleaved 2-unrolled
//   loops = 4 independent chains the scheduler cannot merge. No LDS, no
//   barrier, no cross-wave combine. bf16 loads (validated R11, absmax
//   1.95e-3 passed). Falsifier: VGPR<=16 & dur>=65 => inline-asm next.

constexpr int KDIM = 128;   // inner dim of all three GEMMs
constexpr int NGRAPH = 64;

__device__ __forceinline__ unsigned bf16rne(float f) {
  unsigned u = __float_as_uint(f);
  return (u + 0x7fffu + ((u >> 16) & 1u)) >> 16;  // finite values only
}
__device__ __forceinline__ unsigned packbf2(float a, float b) {
  return bf16rne(a) | (bf16rne(b) << 16);
}
__device__ __forceinline__ float bflo(unsigned u) {
  return __uint_as_float(u << 16);
}
__device__ __forceinline__ float bfhi(unsigned u) {
  return __uint_as_float(u & 0xffff0000u);
}

__global__ void k_init(int* __restrict__ counts, int n) {
  int i = blockIdx.x * blockDim.x + threadIdx.x;
  int stride = gridDim.x * blockDim.x;
  for (int j = i; j < n; j += stride) counts[j] = 0;
}

__global__ void k_hist(const int* __restrict__ src, const int* __restrict__ dst,
                       int* __restrict__ counts, int e, int n) {
  int i = blockIdx.x * blockDim.x + threadIdx.x;
  int stride = gridDim.x * blockDim.x;
  for (int j = i; j < e; j += stride) {
    int s = src[j], d = dst[j];
    if ((unsigned)s < (unsigned)n && (unsigned)d < (unsigned)n)
      atomicAdd(&counts[d], 1);
  }
}

__global__ void k_dis(const int* __restrict__ counts, float* __restrict__ dis, int n) {
  int i = blockIdx.x * blockDim.x + threadIdx.x;
  int stride = gridDim.x * blockDim.x;
  for (int j = i; j < n; j += stride)
    dis[j] = rsqrtf((float)counts[j] + 1.0f);
}

// per-block exclusive scan; blockSums[b] = block total
__global__ void k_scan_block(const int* __restrict__ in, int* __restrict__ outExcl,
                             int* __restrict__ blockSums, int n) {
  __shared__ int s[256];
  int tid = threadIdx.x;
  int i = blockIdx.x * 256 + tid;
  int v = (i < n) ? in[i] : 0;
  int x = v;
  s[tid] = x;
  __syncthreads();
  for (int off = 1; off < 256; off <<= 1) {
    int t = (tid >= off) ? s[tid - off] : 0;
    __syncthreads();
    x += t;
    s[tid] = x;
    __syncthreads();
  }
  if (i < n) outExcl[i] = x - v;
  if (tid == 255) blockSums[blockIdx.x] = x;
}

__global__ void k_scan_offsets(int* __restrict__ bs, int nb) {
  __shared__ int s[256];
  int tid = threadIdx.x;
  int v = (tid < nb) ? bs[tid] : 0;
  int x = v;
  s[tid] = x;
  __syncthreads();
  for (int off = 1; off < 256; off <<= 1) {
    int t = (tid >= off) ? s[tid - off] : 0;
    __syncthreads();
    x += t;
    s[tid] = x;
    __syncthreads();
  }
  if (tid < nb) bs[tid] = x - v;
  if (tid == nb - 1) bs[256] = x;  // total valid edges
}

__global__ void k_scan_add(int* __restrict__ row_start, const int* __restrict__ bs,
                           int* __restrict__ cursor, int n) {
  int i = blockIdx.x * blockDim.x + threadIdx.x;
  int stride = gridDim.x * blockDim.x;
  for (int j = i; j < n; j += stride) {
    int r = row_start[j] + bs[j >> 8];
    row_start[j] = r;
    cursor[j] = r;
  }
  if (i == 0) row_start[n] = bs[256];
}

__global__ void k_scatter(const int* __restrict__ src, const int* __restrict__ dst,
                          int* __restrict__ cursor, int* __restrict__ colA,
                          int e, int n) {
  int i = blockIdx.x * blockDim.x + threadIdx.x;
  int stride = gridDim.x * blockDim.x;
  for (int j = i; j < e; j += stride) {
    int s = src[j], d = dst[j];
    if ((unsigned)s < (unsigned)n && (unsigned)d < (unsigned)n) {
      int pos = atomicAdd(&cursor[d], 1);
      colA[pos] = s;
    }
  }
}

// H = X @ W.  Block tile 128 rows x 64 cols, BK=32; bf16 output (R11).
template <int DOUT>
__global__ __launch_bounds__(256) void k_gemm2b(const float* __restrict__ X,
                                                const float* __restrict__ W,
                                                unsigned short* __restrict__ Hb,
                                                int n) {
  __shared__ float xT[32][128];  // 16 KB
  __shared__ float Wl[32][64];   // 8 KB
  const int tid = threadIdx.x;
  const int tr = tid & 15;
  const int tc = tid >> 4;
  const int rowBase = blockIdx.x * 128;
  const int colBase = blockIdx.y * 64;

  float acc[8][4];
#pragma unroll
  for (int i = 0; i < 8; ++i)
#pragma unroll
    for (int j = 0; j < 4; ++j) acc[i][j] = 0.f;

  const int sr = tid >> 1;
  const int kh = (tid & 1) * 16;
  const int srow = min(rowBase + sr, n - 1);
  const float* xsrc = X + (size_t)srow * KDIM + kh;

  for (int k0 = 0; k0 < KDIM / 32; ++k0) {
    {
      const float4* s4 = reinterpret_cast<const float4*>(xsrc + k0 * 32);
      float4 v0 = s4[0], v1 = s4[1], v2 = s4[2], v3 = s4[3];
      xT[kh + 0][sr] = v0.x;  xT[kh + 1][sr] = v0.y;
      xT[kh + 2][sr] = v0.z;  xT[kh + 3][sr] = v0.w;
      xT[kh + 4][sr] = v1.x;  xT[kh + 5][sr] = v1.y;
      xT[kh + 6][sr] = v1.z;  xT[kh + 7][sr] = v1.w;
      xT[kh + 8][sr] = v2.x;  xT[kh + 9][sr] = v2.y;
      xT[kh + 10][sr] = v2.z; xT[kh + 11][sr] = v2.w;
      xT[kh + 12][sr] = v3.x; xT[kh + 13][sr] = v3.y;
      xT[kh + 14][sr] = v3.z; xT[kh + 15][sr] = v3.w;
    }
#pragma unroll
    for (int q = 0; q < 2; ++q) {
      int f4 = tid + q * 256;
      int k = f4 >> 4;
      int c4 = f4 & 15;
      *reinterpret_cast<float4*>(&Wl[k][c4 * 4]) = *reinterpret_cast<const float4*>(
          W + (size_t)(k0 * 32 + k) * DOUT + colBase + c4 * 4);
    }
    __syncthreads();
#pragma unroll 8
    for (int k = 0; k < 32; ++k) {
      float4 xa = *reinterpret_cast<const float4*>(&xT[k][tr * 4]);
      float4 xb = *reinterpret_cast<const float4*>(&xT[k][64 + tr * 4]);
      float4 wv = *reinterpret_cast<const float4*>(&Wl[k][tc * 4]);
      const float xs[8] = {xa.x, xa.y, xa.z, xa.w, xb.x, xb.y, xb.z, xb.w};
      const float ws[4] = {wv.x, wv.y, wv.z, wv.w};
#pragma unroll
      for (int i = 0; i < 8; ++i)
#pragma unroll
        for (int j = 0; j < 4; ++j) acc[i][j] = fmaf(xs[i], ws[j], acc[i][j]);
    }
    __syncthreads();
  }

#pragma unroll
  for (int i = 0; i < 8; ++i) {
    int row = rowBase + ((i < 4) ? (tr * 4 + i) : (64 + tr * 4 + i - 4));
    if (row < n) {
      uint2 o;
      o.x = packbf2(acc[i][0], acc[i][1]);
      o.y = packbf2(acc[i][2], acc[i][3]);
      *reinterpret_cast<uint2*>(Hb + (size_t)row * DOUT + colBase + tc * 4) = o;
    }
  }
}

// R12 aggregation: each wave owns TWO nodes, loops interleaved + 2-unrolled
// = 4 independent gather chains (separate accumulators & loop state).
// No LDS, no barrier. bf16 H loads, f32 accumulate.
// D=128: lane's dword = dims {2*lane, 2*lane+1}. D=64: lane's ushort = dim lane.
template <int D, bool RELU>
__global__ __launch_bounds__(256, 4) void k_agg7(
    const unsigned short* __restrict__ Hb, const int* __restrict__ row_start,
    const int* __restrict__ colA, const float* __restrict__ dis,
    const float* __restrict__ bias, float* __restrict__ OUT, int n) {
  constexpr int C = D / 64;  // 2 (D=128) or 1 (D=64)
  const int wave = threadIdx.x >> 6;
  const int lane = threadIdx.x & 63;
  const int nA = blockIdx.x * 8 + wave * 2;
  const int nB = nA + 1;
  const bool vA = nA < n, vB = nB < n;

  int eA = vA ? row_start[nA] : 0, endA = vA ? row_start[nA + 1] : 0;
  int eB = vB ? row_start[nB] : 0, endB = vB ? row_start[nB + 1] : 0;
  const float diA = vA ? dis[nA] : 0.f;
  const float diB = vB ? dis[nB] : 0.f;

  float aA0[C], aA1[C], aB0[C], aB1[C];
#pragma unroll
  for (int c = 0; c < C; ++c) { aA0[c] = 0.f; aA1[c] = 0.f; aB0[c] = 0.f; aB1[c] = 0.f; }

  auto hload = [&](int s) -> unsigned {
    if constexpr (C == 2)
      return reinterpret_cast<const unsigned*>(Hb + (size_t)s * D)[lane];
    else
      return (unsigned)Hb[(size_t)s * D + lane];
  };
  auto fma1 = [&](float* acc, unsigned u, float w) {
    acc[0] = fmaf(bflo(u), w, acc[0]);
    if constexpr (C == 2) acc[1] = fmaf(bfhi(u), w, acc[1]);
  };

  // main: both nodes, 2-unrolled each -> 4 loads in flight
  while (eA + 1 < endA && eB + 1 < endB) {
    const int sA0 = colA[eA], sA1 = colA[eA + 1];
    const int sB0 = colA[eB], sB1 = colA[eB + 1];
    const float wA0 = dis[sA0] * diA, wA1 = dis[sA1] * diA;
    const float wB0 = dis[sB0] * diB, wB1 = dis[sB1] * diB;
    const unsigned hA0 = hload(sA0), hA1 = hload(sA1);
    const unsigned hB0 = hload(sB0), hB1 = hload(sB1);
    fma1(aA0, hA0, wA0);
    fma1(aA1, hA1, wA1);
    fma1(aB0, hB0, wB0);
    fma1(aB1, hB1, wB1);
    eA += 2; eB += 2;
  }
  // drain A
  while (eA + 1 < endA) {
    const int s0 = colA[eA], s1 = colA[eA + 1];
    const float w0 = dis[s0] * diA, w1 = dis[s1] * diA;
    const unsigned h0 = hload(s0), h1 = hload(s1);
    fma1(aA0, h0, w0);
    fma1(aA1, h1, w1);
    eA += 2;
  }
  if (eA < endA) {
    const int s0 = colA[eA];
    fma1(aA0, hload(s0), dis[s0] * diA);
  }
  // drain B
  while (eB + 1 < endB) {
    const int s0 = colA[eB], s1 = colA[eB + 1];
    const float w0 = dis[s0] * diB, w1 = dis[s1] * diB;
    const unsigned h0 = hload(s0), h1 = hload(s1);
    fma1(aB0, h0, w0);
    fma1(aB1, h1, w1);
    eB += 2;
  }
  if (eB < endB) {
    const int s0 = colA[eB];
    fma1(aB0, hload(s0), dis[s0] * diB);
  }

  // epilogue
  if (vA) {
    const unsigned u = hload(nA);
    const float di2 = diA * diA;
#pragma unroll
    for (int c = 0; c < C; ++c) {
      float h = (c == 0) ? bflo(u) : bfhi(u);
      float v = aA0[c] + aA1[c] + h * di2 + bias[C * lane + c];
      if (RELU) v = fmaxf(v, 0.f);
      OUT[(size_t)nA * D + C * lane + c] = v;
    }
  }
  if (vB) {
    const unsigned u = hload(nB);
    const float di2 = diB * diB;
#pragma unroll
    for (int c = 0; c < C; ++c) {
      float h = (c == 0) ? bflo(u) : bfhi(u);
      float v = aB0[c] + aB1[c] + h * di2 + bias[C * lane + c];
      if (RELU) v = fmaxf(v, 0.f);
      OUT[(size_t)nB * D + C * lane + c] = v;
    }
  }
}

// batch sorted -> one block per graph, binary-search range, no atomics.
__global__ __launch_bounds__(256) void k_pool2(const float* __restrict__ F,
                                               const int* __restrict__ batch,
                                               float* __restrict__ out, int n) {
  const int g = blockIdx.x;
  __shared__ int sb[2];
  if (threadIdx.x < 2) {
    int target = g + threadIdx.x;
    int lo = 0, hi = n;
    while (lo < hi) {
      int mid = (lo + hi) >> 1;
      if (batch[mid] < target) lo = mid + 1; else hi = mid;
    }
    sb[threadIdx.x] = lo;
  }
  __syncthreads();
  const int beg = sb[0], end = sb[1];
  const int wave = threadIdx.x >> 6;
  const int lane = threadIdx.x & 63;
  float acc = 0.f;
  for (int node = beg + wave; node < end; node += 4)
    acc += F[(size_t)node * 64 + lane];
  __shared__ float red[4][64];
  red[wave][lane] = acc;
  __syncthreads();
  if (wave == 0) {
    float v = (red[0][lane] + red[1][lane]) + (red[2][lane] + red[3][lane]);
    out[g * 64 + lane] = v / fmaxf((float)(end - beg), 1.f);
  }
}

extern "C" void kernel_launch(void* const* d_in, const int* in_sizes, int n_in,
                              void* d_out, int out_size, void* d_ws, size_t ws_size,
                              hipStream_t stream) {
  const float* x     = (const float*)d_in[0];
  const int*   ei    = (const int*)d_in[1];
  const int*   batch = (const int*)d_in[2];
  const float* W1 = (const float*)d_in[3];
  const float* b1 = (const float*)d_in[4];
  const float* W2 = (const float*)d_in[5];
  const float* b2 = (const float*)d_in[6];
  const float* W3 = (const float*)d_in[7];
  const float* b3 = (const float*)d_in[8];

  const int n = in_sizes[0] / KDIM;   // 50000
  const int e = in_sizes[1] / 2;      // 800000
  const int* src = ei;
  const int* dst = ei + e;

  char* p = (char*)d_ws;
  size_t off = 0;
  auto carve = [&](size_t bytes) {
    char* r = p + off;
    off = (off + bytes + 255) & ~(size_t)255;
    return r;
  };
  unsigned short* Hb = (unsigned short*)carve((size_t)n * KDIM * 2);  // bf16 H
  float* F           = (float*)carve((size_t)n * KDIM * 4);           // f32 relu out
  float* dis         = (float*)carve((size_t)n * 4);
  int*   counts      = (int*)carve((size_t)n * 4);
  int*   row_start   = (int*)carve((size_t)(n + 1) * 4);
  int*   cursor      = (int*)carve((size_t)n * 4);
  int*   colA        = (int*)carve((size_t)e * 4);
  int*   blockSums   = (int*)carve(512 * 4);
  (void)ws_size;

  const int nb1 = (n + 255) / 256;
  const int GS = 1024;

  k_init<<<GS, 256, 0, stream>>>(counts, n);
  k_hist<<<GS, 256, 0, stream>>>(src, dst, counts, e, n);
  k_dis<<<nb1, 256, 0, stream>>>(counts, dis, n);
  k_scan_block<<<nb1, 256, 0, stream>>>(counts, row_start, blockSums, n);
  k_scan_offsets<<<1, 256, 0, stream>>>(blockSums, nb1);
  k_scan_add<<<nb1, 256, 0, stream>>>(row_start, blockSums, cursor, n);
  k_scatter<<<GS, 256, 0, stream>>>(src, dst, cursor, colA, e, n);

  const int rowBlocks = (n + 127) / 128;  // 391
  const int aggGrid = (n + 7) / 8;        // 8 nodes per block (2 per wave)

  // layer 1
  k_gemm2b<128><<<dim3(rowBlocks, 2), 256, 0, stream>>>(x, W1, Hb, n);
  k_agg7<128, true><<<aggGrid, 256, 0, stream>>>(Hb, row_start, colA, dis, b1, F, n);
  // layer 2
  k_gemm2b<128><<<dim3(rowBlocks, 2), 256, 0, stream>>>(F, W2, Hb, n);
  k_agg7<128, true><<<aggGrid, 256, 0, stream>>>(Hb, row_start, colA, dis, b2, F, n);
  // layer 3
  k_gemm2b<64><<<dim3(rowBlocks, 1), 256, 0, stream>>>(F, W3, Hb, n);
  k_agg7<64, false><<<aggGrid, 256, 0, stream>>>(Hb, row_start, colA, dis, b3,
                                                 (float*)d_out, n);
  // pooling
  k_pool2<<<NGRAPH, 256, 0, stream>>>((const float*)d_out, batch,
                                      (float*)d_out + (size_t)n * 64, n);
}

// Round 13
// 425.766 us; speedup vs baseline: 1.9488x; 1.0482x over previous
//
#include <hip/hip_runtime.h>

// GCN 3-layer + mean pool, MI355X.
// R1: pool atomics -> segmented reduction (1106 -> 764us).
// R2: k_gemm rewrite 128x64 tile.
// R5-R12 agg ladder: ... -> agg7 (2 nodes/wave, 4 indep chains) left top-5
//   (<61us). Latency model validated: independent accumulators = chains.
// R12 post-mortem: k_scatter 62us top. WRITE_SIZE 53MB = 64B/edge — every
//   4B colA write evicts a full line (random writes from all 8 XCDs'
//   non-coherent L2s). VALUBusy 0.35%, FETCH 3.4MB: pure write-amp.
// R13: partition hist+scatter by dst-range keyed to blockIdx&7 (XCD
//   round-robin heuristic): partition's colA region ~400KB written only by
//   one XCD's blocks -> lines fill 16/16 in L2. Cost: 8x sequential edge
//   re-reads (L3-absorbed). Falsifier: WRITE_SIZE stays ~53MB.

constexpr int KDIM = 128;   // inner dim of all three GEMMs
constexpr int NGRAPH = 64;
constexpr int NPART = 8;    // dst-range partitions (XCD count)

__device__ __forceinline__ unsigned bf16rne(float f) {
  unsigned u = __float_as_uint(f);
  return (u + 0x7fffu + ((u >> 16) & 1u)) >> 16;  // finite values only
}
__device__ __forceinline__ unsigned packbf2(float a, float b) {
  return bf16rne(a) | (bf16rne(b) << 16);
}
__device__ __forceinline__ float bflo(unsigned u) {
  return __uint_as_float(u << 16);
}
__device__ __forceinline__ float bfhi(unsigned u) {
  return __uint_as_float(u & 0xffff0000u);
}

__global__ void k_init(int* __restrict__ counts, int n) {
  int i = blockIdx.x * blockDim.x + threadIdx.x;
  int stride = gridDim.x * blockDim.x;
  for (int j = i; j < n; j += stride) counts[j] = 0;
}

// Partitioned histogram: partition p = blockIdx&7 owns dst range
// [p*chunk, (p+1)*chunk); its blocks grid-stride the WHOLE edge list and
// filter. counts atomics stay in one partition's 25KB region.
__global__ void k_hist_p(const int* __restrict__ dst, int* __restrict__ counts,
                         int e, int n, int chunk) {
  const int p = blockIdx.x & (NPART - 1);
  const int inst = blockIdx.x >> 3;
  const int nInst = gridDim.x >> 3;
  const int lo = p * chunk;
  const int hi = min(n, lo + chunk);
  int i = inst * blockDim.x + threadIdx.x;
  const int stride = nInst * blockDim.x;
  for (int j = i; j < e; j += stride) {
    const int d = dst[j];
    if (d >= lo && d < hi) atomicAdd(&counts[d], 1);
  }
}

__global__ void k_dis(const int* __restrict__ counts, float* __restrict__ dis, int n) {
  int i = blockIdx.x * blockDim.x + threadIdx.x;
  int stride = gridDim.x * blockDim.x;
  for (int j = i; j < n; j += stride)
    dis[j] = rsqrtf((float)counts[j] + 1.0f);
}

// per-block exclusive scan; blockSums[b] = block total
__global__ void k_scan_block(const int* __restrict__ in, int* __restrict__ outExcl,
                             int* __restrict__ blockSums, int n) {
  __shared__ int s[256];
  int tid = threadIdx.x;
  int i = blockIdx.x * 256 + tid;
  int v = (i < n) ? in[i] : 0;
  int x = v;
  s[tid] = x;
  __syncthreads();
  for (int off = 1; off < 256; off <<= 1) {
    int t = (tid >= off) ? s[tid - off] : 0;
    __syncthreads();
    x += t;
    s[tid] = x;
    __syncthreads();
  }
  if (i < n) outExcl[i] = x - v;
  if (tid == 255) blockSums[blockIdx.x] = x;
}

__global__ void k_scan_offsets(int* __restrict__ bs, int nb) {
  __shared__ int s[256];
  int tid = threadIdx.x;
  int v = (tid < nb) ? bs[tid] : 0;
  int x = v;
  s[tid] = x;
  __syncthreads();
  for (int off = 1; off < 256; off <<= 1) {
    int t = (tid >= off) ? s[tid - off] : 0;
    __syncthreads();
    x += t;
    s[tid] = x;
    __syncthreads();
  }
  if (tid < nb) bs[tid] = x - v;
  if (tid == nb - 1) bs[256] = x;  // total valid edges
}

__global__ void k_scan_add(int* __restrict__ row_start, const int* __restrict__ bs,
                           int* __restrict__ cursor, int n) {
  int i = blockIdx.x * blockDim.x + threadIdx.x;
  int stride = gridDim.x * blockDim.x;
  for (int j = i; j < n; j += stride) {
    int r = row_start[j] + bs[j >> 8];
    row_start[j] = r;
    cursor[j] = r;
  }
  if (i == 0) row_start[n] = bs[256];
}

// Partitioned scatter: same partition scheme; colA writes confined to the
// partition's contiguous region -> full-line fills inside one XCD's L2.
__global__ void k_scatter_p(const int* __restrict__ src, const int* __restrict__ dst,
                            int* __restrict__ cursor, int* __restrict__ colA,
                            int e, int n, int chunk) {
  const int p = blockIdx.x & (NPART - 1);
  const int inst = blockIdx.x >> 3;
  const int nInst = gridDim.x >> 3;
  const int lo = p * chunk;
  const int hi = min(n, lo + chunk);
  int i = inst * blockDim.x + threadIdx.x;
  const int stride = nInst * blockDim.x;
  for (int j = i; j < e; j += stride) {
    const int d = dst[j];
    if (d >= lo && d < hi) {
      const int s = src[j];
      if ((unsigned)s < (unsigned)n) {
        int pos = atomicAdd(&cursor[d], 1);
        colA[pos] = s;
      }
    }
  }
}

// H = X @ W.  Block tile 128 rows x 64 cols, BK=32; bf16 output (R11).
template <int DOUT>
__global__ __launch_bounds__(256) void k_gemm2b(const float* __restrict__ X,
                                                const float* __restrict__ W,
                                                unsigned short* __restrict__ Hb,
                                                int n) {
  __shared__ float xT[32][128];  // 16 KB
  __shared__ float Wl[32][64];   // 8 KB
  const int tid = threadIdx.x;
  const int tr = tid & 15;
  const int tc = tid >> 4;
  const int rowBase = blockIdx.x * 128;
  const int colBase = blockIdx.y * 64;

  float acc[8][4];
#pragma unroll
  for (int i = 0; i < 8; ++i)
#pragma unroll
    for (int j = 0; j < 4; ++j) acc[i][j] = 0.f;

  const int sr = tid >> 1;
  const int kh = (tid & 1) * 16;
  const int srow = min(rowBase + sr, n - 1);
  const float* xsrc = X + (size_t)srow * KDIM + kh;

  for (int k0 = 0; k0 < KDIM / 32; ++k0) {
    {
      const float4* s4 = reinterpret_cast<const float4*>(xsrc + k0 * 32);
      float4 v0 = s4[0], v1 = s4[1], v2 = s4[2], v3 = s4[3];
      xT[kh + 0][sr] = v0.x;  xT[kh + 1][sr] = v0.y;
      xT[kh + 2][sr] = v0.z;  xT[kh + 3][sr] = v0.w;
      xT[kh + 4][sr] = v1.x;  xT[kh + 5][sr] = v1.y;
      xT[kh + 6][sr] = v1.z;  xT[kh + 7][sr] = v1.w;
      xT[kh + 8][sr] = v2.x;  xT[kh + 9][sr] = v2.y;
      xT[kh + 10][sr] = v2.z; xT[kh + 11][sr] = v2.w;
      xT[kh + 12][sr] = v3.x; xT[kh + 13][sr] = v3.y;
      xT[kh + 14][sr] = v3.z; xT[kh + 15][sr] = v3.w;
    }
#pragma unroll
    for (int q = 0; q < 2; ++q) {
      int f4 = tid + q * 256;
      int k = f4 >> 4;
      int c4 = f4 & 15;
      *reinterpret_cast<float4*>(&Wl[k][c4 * 4]) = *reinterpret_cast<const float4*>(
          W + (size_t)(k0 * 32 + k) * DOUT + colBase + c4 * 4);
    }
    __syncthreads();
#pragma unroll 8
    for (int k = 0; k < 32; ++k) {
      float4 xa = *reinterpret_cast<const float4*>(&xT[k][tr * 4]);
      float4 xb = *reinterpret_cast<const float4*>(&xT[k][64 + tr * 4]);
      float4 wv = *reinterpret_cast<const float4*>(&Wl[k][tc * 4]);
      const float xs[8] = {xa.x, xa.y, xa.z, xa.w, xb.x, xb.y, xb.z, xb.w};
      const float ws[4] = {wv.x, wv.y, wv.z, wv.w};
#pragma unroll
      for (int i = 0; i < 8; ++i)
#pragma unroll
        for (int j = 0; j < 4; ++j) acc[i][j] = fmaf(xs[i], ws[j], acc[i][j]);
    }
    __syncthreads();
  }

#pragma unroll
  for (int i = 0; i < 8; ++i) {
    int row = rowBase + ((i < 4) ? (tr * 4 + i) : (64 + tr * 4 + i - 4));
    if (row < n) {
      uint2 o;
      o.x = packbf2(acc[i][0], acc[i][1]);
      o.y = packbf2(acc[i][2], acc[i][3]);
      *reinterpret_cast<uint2*>(Hb + (size_t)row * DOUT + colBase + tc * 4) = o;
    }
  }
}

// R12 aggregation (kept): each wave owns TWO nodes, interleaved 2-unrolled
// = 4 independent gather chains. No LDS/barrier. bf16 loads, f32 accum.
template <int D, bool RELU>
__global__ __launch_bounds__(256, 4) void k_agg7(
    const unsigned short* __restrict__ Hb, const int* __restrict__ row_start,
    const int* __restrict__ colA, const float* __restrict__ dis,
    const float* __restrict__ bias, float* __restrict__ OUT, int n) {
  constexpr int C = D / 64;  // 2 (D=128) or 1 (D=64)
  const int wave = threadIdx.x >> 6;
  const int lane = threadIdx.x & 63;
  const int nA = blockIdx.x * 8 + wave * 2;
  const int nB = nA + 1;
  const bool vA = nA < n, vB = nB < n;

  int eA = vA ? row_start[nA] : 0, endA = vA ? row_start[nA + 1] : 0;
  int eB = vB ? row_start[nB] : 0, endB = vB ? row_start[nB + 1] : 0;
  const float diA = vA ? dis[nA] : 0.f;
  const float diB = vB ? dis[nB] : 0.f;

  float aA0[C], aA1[C], aB0[C], aB1[C];
#pragma unroll
  for (int c = 0; c < C; ++c) { aA0[c] = 0.f; aA1[c] = 0.f; aB0[c] = 0.f; aB1[c] = 0.f; }

  auto hload = [&](int s) -> unsigned {
    if constexpr (C == 2)
      return reinterpret_cast<const unsigned*>(Hb + (size_t)s * D)[lane];
    else
      return (unsigned)Hb[(size_t)s * D + lane];
  };
  auto fma1 = [&](float* acc, unsigned u, float w) {
    acc[0] = fmaf(bflo(u), w, acc[0]);
    if constexpr (C == 2) acc[1] = fmaf(bfhi(u), w, acc[1]);
  };

  while (eA + 1 < endA && eB + 1 < endB) {
    const int sA0 = colA[eA], sA1 = colA[eA + 1];
    const int sB0 = colA[eB], sB1 = colA[eB + 1];
    const float wA0 = dis[sA0] * diA, wA1 = dis[sA1] * diA;
    const float wB0 = dis[sB0] * diB, wB1 = dis[sB1] * diB;
    const unsigned hA0 = hload(sA0), hA1 = hload(sA1);
    const unsigned hB0 = hload(sB0), hB1 = hload(sB1);
    fma1(aA0, hA0, wA0);
    fma1(aA1, hA1, wA1);
    fma1(aB0, hB0, wB0);
    fma1(aB1, hB1, wB1);
    eA += 2; eB += 2;
  }
  while (eA + 1 < endA) {
    const int s0 = colA[eA], s1 = colA[eA + 1];
    const float w0 = dis[s0] * diA, w1 = dis[s1] * diA;
    const unsigned h0 = hload(s0), h1 = hload(s1);
    fma1(aA0, h0, w0);
    fma1(aA1, h1, w1);
    eA += 2;
  }
  if (eA < endA) {
    const int s0 = colA[eA];
    fma1(aA0, hload(s0), dis[s0] * diA);
  }
  while (eB + 1 < endB) {
    const int s0 = colA[eB], s1 = colA[eB + 1];
    const float w0 = dis[s0] * diB, w1 = dis[s1] * diB;
    const unsigned h0 = hload(s0), h1 = hload(s1);
    fma1(aB0, h0, w0);
    fma1(aB1, h1, w1);
    eB += 2;
  }
  if (eB < endB) {
    const int s0 = colA[eB];
    fma1(aB0, hload(s0), dis[s0] * diB);
  }

  if (vA) {
    const unsigned u = hload(nA);
    const float di2 = diA * diA;
#pragma unroll
    for (int c = 0; c < C; ++c) {
      float h = (c == 0) ? bflo(u) : bfhi(u);
      float v = aA0[c] + aA1[c] + h * di2 + bias[C * lane + c];
      if (RELU) v = fmaxf(v, 0.f);
      OUT[(size_t)nA * D + C * lane + c] = v;
    }
  }
  if (vB) {
    const unsigned u = hload(nB);
    const float di2 = diB * diB;
#pragma unroll
    for (int c = 0; c < C; ++c) {
      float h = (c == 0) ? bflo(u) : bfhi(u);
      float v = aB0[c] + aB1[c] + h * di2 + bias[C * lane + c];
      if (RELU) v = fmaxf(v, 0.f);
      OUT[(size_t)nB * D + C * lane + c] = v;
    }
  }
}

// batch sorted -> one block per graph, binary-search range, no atomics.
__global__ __launch_bounds__(256) void k_pool2(const float* __restrict__ F,
                                               const int* __restrict__ batch,
                                               float* __restrict__ out, int n) {
  const int g = blockIdx.x;
  __shared__ int sb[2];
  if (threadIdx.x < 2) {
    int target = g + threadIdx.x;
    int lo = 0, hi = n;
    while (lo < hi) {
      int mid = (lo + hi) >> 1;
      if (batch[mid] < target) lo = mid + 1; else hi = mid;
    }
    sb[threadIdx.x] = lo;
  }
  __syncthreads();
  const int beg = sb[0], end = sb[1];
  const int wave = threadIdx.x >> 6;
  const int lane = threadIdx.x & 63;
  float acc = 0.f;
  for (int node = beg + wave; node < end; node += 4)
    acc += F[(size_t)node * 64 + lane];
  __shared__ float red[4][64];
  red[wave][lane] = acc;
  __syncthreads();
  if (wave == 0) {
    float v = (red[0][lane] + red[1][lane]) + (red[2][lane] + red[3][lane]);
    out[g * 64 + lane] = v / fmaxf((float)(end - beg), 1.f);
  }
}

extern "C" void kernel_launch(void* const* d_in, const int* in_sizes, int n_in,
                              void* d_out, int out_size, void* d_ws, size_t ws_size,
                              hipStream_t stream) {
  const float* x     = (const float*)d_in[0];
  const int*   ei    = (const int*)d_in[1];
  const int*   batch = (const int*)d_in[2];
  const float* W1 = (const float*)d_in[3];
  const float* b1 = (const float*)d_in[4];
  const float* W2 = (const float*)d_in[5];
  const float* b2 = (const float*)d_in[6];
  const float* W3 = (const float*)d_in[7];
  const float* b3 = (const float*)d_in[8];

  const int n = in_sizes[0] / KDIM;   // 50000
  const int e = in_sizes[1] / 2;      // 800000
  const int* src = ei;
  const int* dst = ei + e;

  char* p = (char*)d_ws;
  size_t off = 0;
  auto carve = [&](size_t bytes) {
    char* r = p + off;
    off = (off + bytes + 255) & ~(size_t)255;
    return r;
  };
  unsigned short* Hb = (unsigned short*)carve((size_t)n * KDIM * 2);  // bf16 H
  float* F           = (float*)carve((size_t)n * KDIM * 4);           // f32 relu out
  float* dis         = (float*)carve((size_t)n * 4);
  int*   counts      = (int*)carve((size_t)n * 4);
  int*   row_start   = (int*)carve((size_t)(n + 1) * 4);
  int*   cursor      = (int*)carve((size_t)n * 4);
  int*   colA        = (int*)carve((size_t)e * 4);
  int*   blockSums   = (int*)carve(512 * 4);
  (void)ws_size;

  const int nb1 = (n + 255) / 256;
  const int chunk = (n + NPART - 1) / NPART;  // 6250

  k_init<<<512, 256, 0, stream>>>(counts, n);
  k_hist_p<<<1024, 256, 0, stream>>>(dst, counts, e, n, chunk);
  k_dis<<<nb1, 256, 0, stream>>>(counts, dis, n);
  k_scan_block<<<nb1, 256, 0, stream>>>(counts, row_start, blockSums, n);
  k_scan_offsets<<<1, 256, 0, stream>>>(blockSums, nb1);
  k_scan_add<<<nb1, 256, 0, stream>>>(row_start, blockSums, cursor, n);
  k_scatter_p<<<1024, 256, 0, stream>>>(src, dst, cursor, colA, e, n, chunk);

  const int rowBlocks = (n + 127) / 128;  // 391
  const int aggGrid = (n + 7) / 8;        // 8 nodes per block (2 per wave)

  // layer 1
  k_gemm2b<128><<<dim3(rowBlocks, 2), 256, 0, stream>>>(x, W1, Hb, n);
  k_agg7<128, true><<<aggGrid, 256, 0, stream>>>(Hb, row_start, colA, dis, b1, F, n);
  // layer 2
  k_gemm2b<128><<<dim3(rowBlocks, 2), 256, 0, stream>>>(F, W2, Hb, n);
  k_agg7<128, true><<<aggGrid, 256, 0, stream>>>(Hb, row_start, colA, dis, b2, F, n);
  // layer 3
  k_gemm2b<64><<<dim3(rowBlocks, 1), 256, 0, stream>>>(F, W3, Hb, n);
  k_agg7<64, false><<<aggGrid, 256, 0, stream>>>(Hb, row_start, colA, dis, b3,
                                                 (float*)d_out, n);
  // pooling
  k_pool2<<<NGRAPH, 256, 0, stream>>>((const float*)d_out, batch,
                                      (float*)d_out + (size_t)n * 64, n);
}